// Round 2
// baseline (327.393 us; speedup 1.0000x reference)
//
#include <hip/hip_runtime.h>
#include <hip/hip_bf16.h>
#include <math.h>

typedef __bf16 bf16_8 __attribute__((ext_vector_type(8)));
typedef __bf16 bf16_4 __attribute__((ext_vector_type(4)));
typedef float f32x4 __attribute__((ext_vector_type(4)));

#define NDIM 1024
#define BATCH 32
#define MAT_ELEMS (NDIM * NDIM)

__device__ static inline void async_copy16(const void* g, void* l) {
  __builtin_amdgcn_global_load_lds(
      (__attribute__((address_space(1))) void*)g,
      (__attribute__((address_space(3))) void*)l, 16, 0, 0);
}

// C[k][j] = s(k) * cos(pi * k * (2j+1) / 2048), s(0)=1/32, s(k)=sqrt(2)/32
__global__ void gen_dct_mat(__bf16* __restrict__ C) {
  int idx = blockIdx.x * blockDim.x + threadIdx.x;
  int k = idx >> 10;
  int j = idx & 1023;
  int t = (k * (2 * j + 1)) & 4095;  // exact phase reduction mod 2*pi
  float ang = (float)t * 1.5339807878856412e-3f;  // pi/2048
  float s = (k == 0) ? 0.03125f : 0.04419417382415922f;
  C[idx] = (__bf16)(s * cosf(ang));
}

// x[b][j][c] fp32 -> xT[b][c][j] bf16. Tile 64x64, 4x4 per thread in-register
// transpose. Stores: 16 lanes x 8B = 128B contiguous per c-row, 4 rows/instr.
__global__ __launch_bounds__(256) void transpose_cvt(
    const float* __restrict__ x, __bf16* __restrict__ xT) {
  const int b = blockIdx.z;
  const int tj = blockIdx.y * 64;
  const int tc = blockIdx.x * 64;
  const int t = threadIdx.x;
  const int bj = t & 15;   // j-block: lanes 0..15 -> store j-contiguity
  const int bc = t >> 4;   // c-block
  const float* xp = x + (size_t)b * MAT_ELEMS +
                    (size_t)(tj + bj * 4) * NDIM + (tc + bc * 4);
  f32x4 v[4];
#pragma unroll
  for (int r = 0; r < 4; r++) v[r] = *(const f32x4*)(xp + (size_t)r * NDIM);
  __bf16* op = xT + (size_t)b * MAT_ELEMS + (size_t)(tc + bc * 4) * NDIM +
               (tj + bj * 4);
#pragma unroll
  for (int e = 0; e < 4; e++) {
    bf16_4 w;
    w[0] = (__bf16)v[0][e];
    w[1] = (__bf16)v[1][e];
    w[2] = (__bf16)v[2][e];
    w[3] = (__bf16)v[3][e];
    *(bf16_4*)(op + (size_t)e * NDIM) = w;
  }
}

// m97-structure GEMM: out[b] = A(1024x1024, row k, col j) @ xT[b]^T
// A, B both bf16 K-contiguous; staging purely via global_load_lds width=16.
__global__ __launch_bounds__(256) void dct_gemm_bt(
    const __bf16* __restrict__ A, const __bf16* __restrict__ B,
    float* __restrict__ out) {
  __shared__ __align__(64) __bf16 Asm[128 * 32];  // 8 KB, row-major 64B rows
  __shared__ __align__(64) __bf16 Bsm[128 * 32];  // 8 KB

  const int t = threadIdx.x;
  const int wave = t >> 6;
  const int lane = t & 63;
  const int bb = blockIdx.z;
  const int m0 = blockIdx.y * 128;
  const int n0 = blockIdx.x * 128;

  // DMA staging: wave w, issue i covers rows [i*64 + w*16, +16);
  // lane l -> row += l>>2, 16B chunk (l&3). LDS dst = wave-base + lane*16.
  const __bf16* Ag0 =
      A + (size_t)(m0 + wave * 16 + (lane >> 2)) * NDIM + ((lane & 3) * 8);
  const __bf16* Ag1 = Ag0 + (size_t)64 * NDIM;
  const __bf16* Bg0 = B + (size_t)bb * MAT_ELEMS +
                      (size_t)(n0 + wave * 16 + (lane >> 2)) * NDIM +
                      ((lane & 3) * 8);
  const __bf16* Bg1 = Bg0 + (size_t)64 * NDIM;
  __bf16* Al0 = Asm + (wave * 16) * 32;
  __bf16* Al1 = Asm + (64 + wave * 16) * 32;
  __bf16* Bl0 = Bsm + (wave * 16) * 32;
  __bf16* Bl1 = Bsm + (64 + wave * 16) * 32;

  const int row16 = lane & 15;
  const int kq8 = (lane >> 4) * 8;
  const int wm = (wave & 1) * 64;
  const int wn = (wave >> 1) * 64;

  f32x4 acc[4][4] = {};

  for (int k0 = 0; k0 < NDIM; k0 += 32) {
    __syncthreads();  // prior iter's ds_reads done before overwrite
    async_copy16(Ag0 + k0, Al0);
    async_copy16(Ag1 + k0, Al1);
    async_copy16(Bg0 + k0, Bl0);
    async_copy16(Bg1 + k0, Bl1);
    __syncthreads();  // drains vmcnt -> DMA data visible

    bf16_8 af[4], bfr[4];
#pragma unroll
    for (int i = 0; i < 4; i++)
      af[i] = *(const bf16_8*)(Asm + (wm + i * 16 + row16) * 32 + kq8);
#pragma unroll
    for (int j = 0; j < 4; j++)
      bfr[j] = *(const bf16_8*)(Bsm + (wn + j * 16 + row16) * 32 + kq8);
#pragma unroll
    for (int i = 0; i < 4; i++)
#pragma unroll
      for (int j = 0; j < 4; j++)
        acc[i][j] = __builtin_amdgcn_mfma_f32_16x16x32_bf16(af[i], bfr[j],
                                                            acc[i][j], 0, 0, 0);
  }

  // epilogue: C/D layout col = lane&15, row = (lane>>4)*4 + reg
  float* ob = out + (size_t)bb * MAT_ELEMS;
  const int rbase = (lane >> 4) * 4;
  const int cofs = lane & 15;
#pragma unroll
  for (int i = 0; i < 4; i++) {
#pragma unroll
    for (int r = 0; r < 4; r++) {
      int row = m0 + wm + i * 16 + rbase + r;
#pragma unroll
      for (int j = 0; j < 4; j++) {
        int col = n0 + wn + j * 16 + cofs;
        ob[(size_t)row * NDIM + col] = acc[i][j][r];
      }
    }
  }
}

// ---------------- fallback: fused transpose-in-K-loop GEMM (passing R1) ----
#define BSTRIDE 40
__global__ __launch_bounds__(256) void dct_gemm_fused(
    const float* __restrict__ x, const __bf16* __restrict__ A,
    float* __restrict__ out) {
  __shared__ __align__(64) __bf16 Asm[128 * 32];
  __shared__ __align__(64) __bf16 Bsm[128 * BSTRIDE];

  const int t = threadIdx.x;
  const int wave = t >> 6;
  const int lane = t & 63;
  const int bb = blockIdx.z;
  const int m0 = blockIdx.y * 128;
  const int n0 = blockIdx.x * 128;

  const __bf16* Ag0 =
      A + (size_t)(m0 + wave * 16 + (lane >> 2)) * NDIM + ((lane & 3) * 8);
  const __bf16* Ag1 = Ag0 + (size_t)64 * NDIM;
  __bf16* Al0 = Asm + (wave * 16) * 32;
  __bf16* Al1 = Asm + (64 + wave * 16) * 32;

  const int bc = t & 127;
  const int bjg = t >> 7;
  const float* xs =
      x + (size_t)bb * MAT_ELEMS + (size_t)(bjg * 16) * NDIM + (n0 + bc);
  bf16_8* bs0 = (bf16_8*)(Bsm + bc * BSTRIDE + bjg * 16);
  bf16_8* bs1 = (bf16_8*)(Bsm + bc * BSTRIDE + bjg * 16 + 8);

  const int row16 = lane & 15;
  const int kq8 = (lane >> 4) * 8;
  const int wm = (wave & 1) * 64;
  const int wn = (wave >> 1) * 64;

  f32x4 acc[4][4] = {};

  for (int k0 = 0; k0 < NDIM; k0 += 32) {
    __syncthreads();
    async_copy16(Ag0 + k0, Al0);
    async_copy16(Ag1 + k0, Al1);

    const float* xp = xs + (size_t)k0 * NDIM;
    bf16_8 v0, v1;
#pragma unroll
    for (int q = 0; q < 8; q++) {
      v0[q] = (__bf16)xp[(size_t)q * NDIM];
      v1[q] = (__bf16)xp[(size_t)(q + 8) * NDIM];
    }
    *bs0 = v0;
    *bs1 = v1;
    __syncthreads();

    bf16_8 af[4], bfr[4];
#pragma unroll
    for (int i = 0; i < 4; i++)
      af[i] = *(const bf16_8*)(Asm + (wm + i * 16 + row16) * 32 + kq8);
#pragma unroll
    for (int j = 0; j < 4; j++)
      bfr[j] = *(const bf16_8*)(Bsm + (wn + j * 16 + row16) * BSTRIDE + kq8);
#pragma unroll
    for (int i = 0; i < 4; i++)
#pragma unroll
      for (int j = 0; j < 4; j++)
        acc[i][j] = __builtin_amdgcn_mfma_f32_16x16x32_bf16(af[i], bfr[j],
                                                            acc[i][j], 0, 0, 0);
  }

  float* ob = out + (size_t)bb * MAT_ELEMS;
  const int rbase = (lane >> 4) * 4;
  const int cofs = lane & 15;
#pragma unroll
  for (int i = 0; i < 4; i++) {
#pragma unroll
    for (int r = 0; r < 4; r++) {
      int row = m0 + wm + i * 16 + rbase + r;
#pragma unroll
      for (int j = 0; j < 4; j++) {
        int col = n0 + wn + j * 16 + cofs;
        ob[(size_t)row * NDIM + col] = acc[i][j][r];
      }
    }
  }
}

extern "C" void kernel_launch(void* const* d_in, const int* in_sizes, int n_in,
                              void* d_out, int out_size, void* d_ws,
                              size_t ws_size, hipStream_t stream) {
  const float* x = (const float*)d_in[0];
  float* out = (float*)d_out;
  __bf16* Cmat = (__bf16*)d_ws;  // 2 MB
  const size_t cbytes = (size_t)MAT_ELEMS * 2;

  gen_dct_mat<<<dim3(MAT_ELEMS / 256), dim3(256), 0, stream>>>(Cmat);

  // how many batches of bf16 xT fit in the remaining workspace?
  size_t avail = ws_size > cbytes ? ws_size - cbytes : 0;
  int nb = (int)(avail / cbytes);
  if (nb > BATCH) nb = BATCH;

  if (nb >= 1) {
    __bf16* xT = (__bf16*)((char*)d_ws + cbytes);
    for (int b0 = 0; b0 < BATCH; b0 += nb) {
      int n = (BATCH - b0) < nb ? (BATCH - b0) : nb;
      transpose_cvt<<<dim3(16, 16, n), dim3(256), 0, stream>>>(
          x + (size_t)b0 * MAT_ELEMS, xT);
      dct_gemm_bt<<<dim3(8, 8, n), dim3(256), 0, stream>>>(
          Cmat, xT, out + (size_t)b0 * MAT_ELEMS);
    }
  } else {
    // workspace too small for staging: fused fallback
    dct_gemm_fused<<<dim3(8, 8, BATCH), dim3(256), 0, stream>>>(x, Cmat, out);
  }
}